// Round 1
// baseline (735.435 us; speedup 1.0000x reference)
//
#include <hip/hip_runtime.h>
#include <hip/hip_bf16.h>

#define S_LEN 2048
#define D_DIM 64
#define BH    32          // B*H
#define BQ    64          // queries per block (4 waves x 16 rows)
#define BK    64          // keys per k-tile
#define NQT   (S_LEN/BQ)  // 32
#define KSTR  72          // padded LDS stride (bf16 elems) to break bank conflicts
#define NEL   ((size_t)BH * S_LEN * D_DIM)   // 4,194,304 elems per tensor

typedef __attribute__((ext_vector_type(4))) short  short4v;  // 4 bf16 = 8B
typedef __attribute__((ext_vector_type(8))) short  short8;   // 8 bf16 = 16B (MFMA frag)
typedef __attribute__((ext_vector_type(4))) float  floatx4;
typedef __attribute__((ext_vector_type(4))) unsigned int uintx4;

__device__ __forceinline__ unsigned short f2bf(float f) {   // RNE fp32->bf16
    unsigned int u = __builtin_bit_cast(unsigned int, f);
    u += 0x7FFFu + ((u >> 16) & 1u);
    return (unsigned short)(u >> 16);
}
__device__ __forceinline__ float bf2f(short s) {            // bf16 bits -> fp32
    return __builtin_bit_cast(float, ((unsigned int)(unsigned short)s) << 16);
}

// ---- dtype-generic 8-element row loads producing bf16 fragments ----
__device__ __forceinline__ short8 load8(const float* p) {
    floatx4 a = *(const floatx4*)p;
    floatx4 b = *(const floatx4*)(p + 4);
    short8 r;
    r[0]=(short)f2bf(a[0]); r[1]=(short)f2bf(a[1]); r[2]=(short)f2bf(a[2]); r[3]=(short)f2bf(a[3]);
    r[4]=(short)f2bf(b[0]); r[5]=(short)f2bf(b[1]); r[6]=(short)f2bf(b[2]); r[7]=(short)f2bf(b[3]);
    return r;
}
__device__ __forceinline__ short8 load8(const __hip_bfloat16* p) {
    return *(const short8*)p;
}
__device__ __forceinline__ void loadrow8(const float* p, unsigned short o[8]) {
    floatx4 a = *(const floatx4*)p, b = *(const floatx4*)(p + 4);
    o[0]=f2bf(a[0]); o[1]=f2bf(a[1]); o[2]=f2bf(a[2]); o[3]=f2bf(a[3]);
    o[4]=f2bf(b[0]); o[5]=f2bf(b[1]); o[6]=f2bf(b[2]); o[7]=f2bf(b[3]);
}
__device__ __forceinline__ void loadrow8(const __hip_bfloat16* p, unsigned short o[8]) {
    short8 v = *(const short8*)p;
#pragma unroll
    for (int j = 0; j < 8; ++j) o[j] = (unsigned short)v[j];
}

// ============================================================================
// PREP KERNEL: one-time Q,K -> bf16 and V -> V^T bf16 into workspace.
// Grid = 1024 blocks x 256 threads. Block (bh,st) transposes V tile
// [st*64..+64) x [0..64); every block also converts its exact 16-elem/thread
// slice of Q and K (1024*256*16 == NEL exactly).
// ============================================================================
template<typename TIN>
__device__ __forceinline__ void prep_body(const TIN* __restrict__ Q, const TIN* __restrict__ K,
                                          const TIN* __restrict__ V,
                                          unsigned short* __restrict__ Qb,
                                          unsigned short* __restrict__ Kb,
                                          unsigned short* __restrict__ Vtg,
                                          unsigned short (*Lt)[KSTR])
{
    const int tid = threadIdx.x;
    const int bid = blockIdx.x;
    {   // Q/K straight conversion, 16 elems per thread each
        size_t idx = ((size_t)bid * 256 + tid) * 16;
        *(short8*)(Qb + idx)     = load8(Q + idx);
        *(short8*)(Qb + idx + 8) = load8(Q + idx + 8);
        *(short8*)(Kb + idx)     = load8(K + idx);
        *(short8*)(Kb + idx + 8) = load8(K + idx + 8);
    }
    const int bh = bid >> 5, st = bid & 31;
    const TIN* Vb = V + ((size_t)bh * S_LEN + (size_t)st * 64) * D_DIM;
#pragma unroll
    for (int i = 0; i < 2; ++i) {                 // load V tile -> LDS (bf16)
        int flat = tid * 8 + i * 2048;
        int r = flat >> 6, c = flat & 63;
        short8 v = load8(Vb + (size_t)r * D_DIM + c);
        *(short8*)(&Lt[r][c]) = v;
    }
    __syncthreads();
    unsigned short* Vh = Vtg + (size_t)bh * D_DIM * S_LEN;
#pragma unroll
    for (int i = 0; i < 4; ++i) {                 // transposed coalesced write
        int flat = tid * 4 + i * 1024;
        int d = flat >> 6, sj = flat & 63;        // sj multiple of 4
        short4v o;
        o[0] = (short)Lt[sj+0][d]; o[1] = (short)Lt[sj+1][d];
        o[2] = (short)Lt[sj+2][d]; o[3] = (short)Lt[sj+3][d];
        *(short4v*)(Vh + (size_t)d * S_LEN + (size_t)st * 64 + sj) = o;
    }
}

__global__ __launch_bounds__(256)
void prep_kernel(const void* __restrict__ Q, const void* __restrict__ K,
                 const void* __restrict__ V, const void* __restrict__ scp,
                 unsigned short* __restrict__ Qb, unsigned short* __restrict__ Kb,
                 unsigned short* __restrict__ Vtg)
{
    __shared__ unsigned short Lt[64][KSTR];
    const unsigned int sw = *(const unsigned int*)scp;
    if ((sw & 0xFFFFu) == 0u)
        prep_body<float>((const float*)Q, (const float*)K, (const float*)V, Qb, Kb, Vtg, Lt);
    else
        prep_body<__hip_bfloat16>((const __hip_bfloat16*)Q, (const __hip_bfloat16*)K,
                                  (const __hip_bfloat16*)V, Qb, Kb, Vtg, Lt);
}

// ============================================================================
// FAST ATTENTION KERNEL (bf16 pre-staged inputs)
// ============================================================================
__device__ __forceinline__ void ldK(const unsigned short* Kh, int kk0, int tid, uintx4 r[2]) {
    // K tile [kk0..kk0+64) x [0..64) is contiguous in global (row-major D=64)
#pragma unroll
    for (int i = 0; i < 2; ++i)
        r[i] = *(const uintx4*)(Kh + (size_t)kk0 * D_DIM + tid * 8 + i * 2048);
}
__device__ __forceinline__ void ldV(const unsigned short* Vh, int kk0, int tid, uintx4 r[2]) {
    // V^T global layout [D][S]; tile rows d, cols kk0..+64
#pragma unroll
    for (int i = 0; i < 2; ++i) {
        int flat = tid * 8 + i * 2048;
        r[i] = *(const uintx4*)(Vh + (size_t)(flat >> 6) * S_LEN + kk0 + (flat & 63));
    }
}
__device__ __forceinline__ void st2(unsigned short* dst, int tid, const uintx4 r[2]) {
#pragma unroll
    for (int i = 0; i < 2; ++i) {
        int flat = tid * 8 + i * 2048;
        *(uintx4*)(dst + (flat >> 6) * KSTR + (flat & 63)) = r[i];
    }
}

__global__ __launch_bounds__(256, 4)
void attn_fast(const unsigned short* __restrict__ Qb, const unsigned short* __restrict__ Kb,
               const unsigned short* __restrict__ Vtg, const void* __restrict__ scp,
               float* __restrict__ Out, float* __restrict__ W)
{
    __shared__ unsigned short Kl[2][BK * KSTR];   // double-buffered K
    __shared__ unsigned short Vt[D_DIM * KSTR];   // single-buffered V^T
    __shared__ unsigned short Pl[4][16 * KSTR];   // per-wave P scratch

    const int tid  = threadIdx.x;
    const int wave = tid >> 6;
    const int lane = tid & 63;
    const int quad = lane >> 4;
    const int lm   = lane & 15;
    const int idx  = blockIdx.x;
    const int bh   = idx & (BH - 1);
    const int qt   = (NQT - 1) - (idx >> 5);   // heavy causal tiles dispatched first
    const int q0   = qt * BQ;

    // decode scale (same runtime dtype trick as before)
    const unsigned int sw = *(const unsigned int*)scp;
    const bool isf32 = ((sw & 0xFFFFu) == 0u);
    const float sc = isf32 ? __builtin_bit_cast(float, sw)
                           : __builtin_bit_cast(float, (sw & 0xFFFFu) << 16);
    const float sc2 = sc * 1.44269504088896f;   // base-2 softmax

    float* Ob = Out + (size_t)bh * S_LEN * D_DIM;
    float* Wb = W   + (size_t)bh * S_LEN * S_LEN;
    const unsigned short* Qh = Qb  + (size_t)bh * S_LEN * D_DIM;
    const unsigned short* Kh = Kb  + (size_t)bh * S_LEN * D_DIM;
    const unsigned short* Vh = Vtg + (size_t)bh * D_DIM * S_LEN;

    // zero-fill masked weights region (write-only -> nontemporal)
    {
        const int zc = S_LEN - (q0 + BQ);
        floatx4 z4 = {0.f, 0.f, 0.f, 0.f};
        for (int r = 0; r < BQ; ++r) {
            float* wr = Wb + (size_t)(q0 + r) * S_LEN + (q0 + BQ);
            for (int c = tid * 4; c < zc; c += 256 * 4)
                __builtin_nontemporal_store(z4, (floatx4*)(wr + c));
        }
    }

    // Q fragments, resident all kernel
    const int qrow = q0 + wave * 16 + lm;
    const short8 qf0 = *(const short8*)(Qh + (size_t)qrow * D_DIM + quad * 8);
    const short8 qf1 = *(const short8*)(Qh + (size_t)qrow * D_DIM + 32 + quad * 8);

    // =========== PASS 1: row sums (no max -- |s*log2e| <= ~30, exp2 safe) ===========
    // Operand-swapped MFMA: C[k][q] -> lane holds 16 k-values of ONE q-row (q = lm).
    {
        uintx4 kr[2];
        ldK(Kh, 0, tid, kr); st2(Kl[0], tid, kr);
    }
    __syncthreads();

    float ls0 = 0.f, ls1 = 0.f, ls2 = 0.f, ls3 = 0.f;
    for (int kt = 0; kt <= qt; ++kt) {
        const bool pre = (kt < qt);
        uintx4 kreg[2];
        if (pre) ldK(Kh, (kt + 1) * BK, tid, kreg);       // T14: issue early
        const unsigned short* Kc = Kl[kt & 1];
        const int kk0 = kt * BK;
        const bool diag = (kt == qt);
#pragma unroll
        for (int kkt = 0; kkt < 4; ++kkt) {
            floatx4 acc = {0.f, 0.f, 0.f, 0.f};
            short8 b0 = *(const short8*)(Kc + (kkt * 16 + lm) * KSTR + quad * 8);
            short8 b1 = *(const short8*)(Kc + (kkt * 16 + lm) * KSTR + 32 + quad * 8);
            acc = __builtin_amdgcn_mfma_f32_16x16x32_bf16(b0, qf0, acc, 0, 0, 0);
            acc = __builtin_amdgcn_mfma_f32_16x16x32_bf16(b1, qf1, acc, 0, 0, 0);
            float s0 = acc[0] * sc2, s1 = acc[1] * sc2;
            float s2 = acc[2] * sc2, s3 = acc[3] * sc2;
            if (diag) {
                int kg = kk0 + kkt * 16 + quad * 4;        // k-global of acc[0]
                if (kg + 0 > qrow) s0 = -1e30f;
                if (kg + 1 > qrow) s1 = -1e30f;
                if (kg + 2 > qrow) s2 = -1e30f;
                if (kg + 3 > qrow) s3 = -1e30f;
            }
            ls0 += exp2f(s0); ls1 += exp2f(s1);
            ls2 += exp2f(s2); ls3 += exp2f(s3);
        }
        if (pre) st2(Kl[(kt + 1) & 1], tid, kreg);        // T14: write late
        __syncthreads();
    }
    float lsum = (ls0 + ls1) + (ls2 + ls3);
    lsum += __shfl_xor(lsum, 16, 64);
    lsum += __shfl_xor(lsum, 32, 64);
    const float linv = 1.0f / lsum;                       // row sum for q = lm
    float inv_l[4];
    {   // redistribute: this lane's C-layout rows are quad*4+r
        const int srcb = (lane & 48) | ((lane >> 4) << 2);
#pragma unroll
        for (int r = 0; r < 4; ++r) inv_l[r] = __shfl(linv, srcb + r, 64);
    }

    // ================= PASS 2: recompute scores, write W, accumulate O =================
    {
        uintx4 kr[2], vr[2];
        ldK(Kh, 0, tid, kr); ldV(Vh, 0, tid, vr);
        st2(Kl[0], tid, kr); st2(Vt, tid, vr);
    }
    __syncthreads();

    floatx4 oacc[4];
#pragma unroll
    for (int dt = 0; dt < 4; ++dt) oacc[dt] = (floatx4){0.f, 0.f, 0.f, 0.f};
    unsigned short* Plw = Pl[wave];

    for (int kt = 0; kt <= qt; ++kt) {
        const bool pre = (kt < qt);
        uintx4 kreg[2], vreg[2];
        if (pre) { ldK(Kh, (kt + 1) * BK, tid, kreg); ldV(Vh, (kt + 1) * BK, tid, vreg); }
        const unsigned short* Kc = Kl[kt & 1];
        const int kk0 = kt * BK;
        const bool diag = (kt == qt);

#pragma unroll
        for (int kkt = 0; kkt < 4; ++kkt) {               // scores (original order)
            floatx4 acc = {0.f, 0.f, 0.f, 0.f};
            short8 b0 = *(const short8*)(Kc + (kkt * 16 + lm) * KSTR + quad * 8);
            short8 b1 = *(const short8*)(Kc + (kkt * 16 + lm) * KSTR + 32 + quad * 8);
            acc = __builtin_amdgcn_mfma_f32_16x16x32_bf16(qf0, b0, acc, 0, 0, 0);
            acc = __builtin_amdgcn_mfma_f32_16x16x32_bf16(qf1, b1, acc, 0, 0, 0);
#pragma unroll
            for (int r = 0; r < 4; ++r) {
                float s = acc[r] * sc2;
                int rowg = q0 + wave * 16 + quad * 4 + r;
                if (diag && (kk0 + kkt * 16 + lm > rowg)) s = -1e30f;  // exp2 -> 0
                float p = exp2f(s) * inv_l[r];
                Plw[(quad * 4 + r) * KSTR + kkt * 16 + lm] = f2bf(p);
            }
        }
        __asm__ volatile("s_waitcnt lgkmcnt(0)" ::: "memory");   // within-wave LDS visibility

        {   // coalesced fp32 global write of this wave's P tile (16 rows x 64 cols)
            const int rr = lane >> 3, cc = (lane & 7) << 3;
            short8 w0 = *(const short8*)(Plw + rr * KSTR + cc);
            short8 w1 = *(const short8*)(Plw + (8 + rr) * KSTR + cc);
            float* wp0 = Wb + (size_t)(q0 + wave * 16 + rr) * S_LEN + kk0 + cc;
            float* wp1 = wp0 + (size_t)8 * S_LEN;
            floatx4 fa, fb;
#pragma unroll
            for (int j = 0; j < 4; ++j) { fa[j] = bf2f(w0[j]); fb[j] = bf2f(w0[4 + j]); }
            __builtin_nontemporal_store(fa, (floatx4*)wp0);
            __builtin_nontemporal_store(fb, (floatx4*)(wp0 + 4));
#pragma unroll
            for (int j = 0; j < 4; ++j) { fa[j] = bf2f(w1[j]); fb[j] = bf2f(w1[4 + j]); }
            __builtin_nontemporal_store(fa, (floatx4*)wp1);
            __builtin_nontemporal_store(fb, (floatx4*)(wp1 + 4));
        }

#pragma unroll
        for (int c = 0; c < 2; ++c) {                     // O += P * V
            short8 pf = *(const short8*)(Plw + lm * KSTR + c * 32 + quad * 8);
#pragma unroll
            for (int dt = 0; dt < 4; ++dt) {
                short8 vf = *(const short8*)(Vt + (dt * 16 + lm) * KSTR + c * 32 + quad * 8);
                oacc[dt] = __builtin_amdgcn_mfma_f32_16x16x32_bf16(pf, vf, oacc[dt], 0, 0, 0);
            }
        }

        if (pre) {
            st2(Kl[(kt + 1) & 1], tid, kreg);   // other K buffer: safe before barrier
            __syncthreads();                    // A: all waves done reading Vt
            st2(Vt, tid, vreg);                 // overwrite single V buffer
            __syncthreads();                    // B: new K/V visible (vm queue empty here)
        }
    }

    // ---- epilogue: O stored fp32 directly from accumulators (C-layout) ----
#pragma unroll
    for (int dt = 0; dt < 4; ++dt)
#pragma unroll
        for (int r = 0; r < 4; ++r)
            Ob[(size_t)(q0 + wave * 16 + quad * 4 + r) * D_DIM + dt * 16 + lm] = oacc[dt][r];
}

// ============================================================================
// FALLBACK (verified previous kernel) -- used only if ws_size is too small
// ============================================================================
template<typename TIN>
__device__ __forceinline__ void stageK(const TIN* Kb, int kk0, __hip_bfloat16* Kl, int tid) {
    if constexpr (sizeof(TIN) == 4) {
#pragma unroll
        for (int i = 0; i < 4; ++i) {
            int flat = tid * 4 + i * 1024;
            int row = flat >> 6, col = flat & 63;
            floatx4 v = *(const floatx4*)((const float*)Kb + (size_t)(kk0 + row) * D_DIM + col);
            short4v s;
            s[0]=(short)f2bf(v[0]); s[1]=(short)f2bf(v[1]);
            s[2]=(short)f2bf(v[2]); s[3]=(short)f2bf(v[3]);
            *(short4v*)(&Kl[row * KSTR + col]) = s;
        }
    } else {
#pragma unroll
        for (int i = 0; i < 2; ++i) {
            int flat = tid * 8 + i * 2048;
            int row = flat >> 6, col = flat & 63;
            *(uintx4*)(&Kl[row * KSTR + col]) =
                *(const uintx4*)((const __hip_bfloat16*)Kb + (size_t)(kk0 + row) * D_DIM + col);
        }
    }
}

template<typename TIN>
__device__ __forceinline__ void attn_body(
    const TIN* __restrict__ Qb, const TIN* __restrict__ Kb, const TIN* __restrict__ Vb,
    float sc2, float* __restrict__ Ob, float* __restrict__ Wb,
    int q0, int qt, __hip_bfloat16* Kl, __hip_bfloat16* Vt, __hip_bfloat16* Plw)
{
    const int tid  = threadIdx.x;
    const int wave = tid >> 6;
    const int lane = tid & 63;
    const int quad = lane >> 4;
    const int lm   = lane & 15;

    const int qrow = q0 + wave * 16 + lm;
    short8 qfrag0 = load8(Qb + (size_t)qrow * D_DIM + quad * 8);
    short8 qfrag1 = load8(Qb + (size_t)qrow * D_DIM + 32 + quad * 8);

    float mrow[4], lrow[4];
#pragma unroll
    for (int r = 0; r < 4; ++r) { mrow[r] = -1e30f; lrow[r] = 0.f; }

    for (int kt = 0; kt <= qt; ++kt) {
        const int kk0 = kt * BK;
        __syncthreads();
        stageK(Kb, kk0, Kl, tid);
        __syncthreads();

        const bool diag = (kt == qt);
        float s[4][4];
#pragma unroll
        for (int kkt = 0; kkt < 4; ++kkt) {
            floatx4 acc = {0.f, 0.f, 0.f, 0.f};
            short8 b0 = *(const short8*)(&Kl[(kkt * 16 + lm) * KSTR + quad * 8]);
            short8 b1 = *(const short8*)(&Kl[(kkt * 16 + lm) * KSTR + 32 + quad * 8]);
            acc = __builtin_amdgcn_mfma_f32_16x16x32_bf16(qfrag0, b0, acc, 0, 0, 0);
            acc = __builtin_amdgcn_mfma_f32_16x16x32_bf16(qfrag1, b1, acc, 0, 0, 0);
#pragma unroll
            for (int r = 0; r < 4; ++r) s[kkt][r] = acc[r] * sc2;
            if (diag) {
                int colg = kk0 + kkt * 16 + lm;
#pragma unroll
                for (int r = 0; r < 4; ++r) {
                    int rowg = q0 + wave * 16 + quad * 4 + r;
                    if (colg > rowg) s[kkt][r] = -1e30f;
                }
            }
        }
#pragma unroll
        for (int r = 0; r < 4; ++r) {
            float mx = fmaxf(fmaxf(s[0][r], s[1][r]), fmaxf(s[2][r], s[3][r]));
#pragma unroll
            for (int off = 1; off < 16; off <<= 1)
                mx = fmaxf(mx, __shfl_xor(mx, off, 64));
            float mnew = fmaxf(mrow[r], mx);
            float p = exp2f(s[0][r] - mnew) + exp2f(s[1][r] - mnew) +
                      exp2f(s[2][r] - mnew) + exp2f(s[3][r] - mnew);
#pragma unroll
            for (int off = 1; off < 16; off <<= 1)
                p += __shfl_xor(p, off, 64);
            lrow[r] = lrow[r] * exp2f(mrow[r] - mnew) + p;
            mrow[r] = mnew;
        }
    }

    float inv_l[4];
#pragma unroll
    for (int r = 0; r < 4; ++r) inv_l[r] = 1.0f / lrow[r];

    floatx4 oacc[4];
#pragma unroll
    for (int dt = 0; dt < 4; ++dt) oacc[dt] = (floatx4){0.f, 0.f, 0.f, 0.f};

    for (int kt = 0; kt <= qt; ++kt) {
        const int kk0 = kt * BK;
        __syncthreads();
        stageK(Kb, kk0, Kl, tid);
        {
            int r = tid & 31, c = (tid >> 5) << 3;
            const TIN* v0 = Vb + (size_t)(kk0 + 2 * r) * D_DIM + c;
            unsigned short a[8], b[8];
            loadrow8(v0, a);
            loadrow8(v0 + D_DIM, b);
#pragma unroll
            for (int j = 0; j < 8; ++j) {
                unsigned int d = (unsigned int)a[j] | ((unsigned int)b[j] << 16);
                *(unsigned int*)(&Vt[(c + j) * KSTR + 2 * r]) = d;
            }
        }
        __syncthreads();

        const bool diag = (kt == qt);
        float s[4][4];
#pragma unroll
        for (int kkt = 0; kkt < 4; ++kkt) {
            floatx4 acc = {0.f, 0.f, 0.f, 0.f};
            short8 b0 = *(const short8*)(&Kl[(kkt * 16 + lm) * KSTR + quad * 8]);
            short8 b1 = *(const short8*)(&Kl[(kkt * 16 + lm) * KSTR + 32 + quad * 8]);
            acc = __builtin_amdgcn_mfma_f32_16x16x32_bf16(qfrag0, b0, acc, 0, 0, 0);
            acc = __builtin_amdgcn_mfma_f32_16x16x32_bf16(qfrag1, b1, acc, 0, 0, 0);
#pragma unroll
            for (int r = 0; r < 4; ++r) s[kkt][r] = acc[r] * sc2;
            if (diag) {
                int colg = kk0 + kkt * 16 + lm;
#pragma unroll
                for (int r = 0; r < 4; ++r) {
                    int rowg = q0 + wave * 16 + quad * 4 + r;
                    if (colg > rowg) s[kkt][r] = -1e30f;
                }
            }
        }
#pragma unroll
        for (int kkt = 0; kkt < 4; ++kkt) {
#pragma unroll
            for (int r = 0; r < 4; ++r) {
                float p = exp2f(s[kkt][r] - mrow[r]) * inv_l[r];
                Plw[(quad * 4 + r) * KSTR + kkt * 16 + lm] =
                    __builtin_bit_cast(__hip_bfloat16, f2bf(p));
            }
        }
        __asm__ volatile("s_waitcnt lgkmcnt(0)" ::: "memory");

        {
            int rr = lane >> 3, cc = (lane & 7) << 3;
            short8 w0 = *(const short8*)(&Plw[rr * KSTR + cc]);
            short8 w1 = *(const short8*)(&Plw[(8 + rr) * KSTR + cc]);
            float* wp0 = Wb + (size_t)(q0 + wave * 16 + rr) * S_LEN + kk0 + cc;
            float* wp1 = Wb + (size_t)(q0 + wave * 16 + 8 + rr) * S_LEN + kk0 + cc;
            floatx4 fa, fb;
#pragma unroll
            for (int j = 0; j < 4; ++j) { fa[j] = bf2f(w0[j]); fb[j] = bf2f(w0[4 + j]); }
            *(floatx4*)wp0 = fa; *(floatx4*)(wp0 + 4) = fb;
#pragma unroll
            for (int j = 0; j < 4; ++j) { fa[j] = bf2f(w1[j]); fb[j] = bf2f(w1[4 + j]); }
            *(floatx4*)wp1 = fa; *(floatx4*)(wp1 + 4) = fb;
        }
#pragma unroll
        for (int c = 0; c < 2; ++c) {
            short8 pf = *(const short8*)(&Plw[lm * KSTR + c * 32 + quad * 8]);
#pragma unroll
            for (int dt = 0; dt < 4; ++dt) {
                short8 vf = *(const short8*)(&Vt[(dt * 16 + lm) * KSTR + c * 32 + quad * 8]);
                oacc[dt] = __builtin_amdgcn_mfma_f32_16x16x32_bf16(pf, vf, oacc[dt], 0, 0, 0);
            }
        }
    }

#pragma unroll
    for (int dt = 0; dt < 4; ++dt)
#pragma unroll
        for (int r = 0; r < 4; ++r)
            Ob[(size_t)(q0 + wave * 16 + quad * 4 + r) * D_DIM + dt * 16 + lm] = oacc[dt][r];
}

__global__ __launch_bounds__(256, 4)
void attn_kernel(const void* __restrict__ Q, const void* __restrict__ K,
                 const void* __restrict__ V, const void* __restrict__ scp,
                 float* __restrict__ Out, float* __restrict__ W)
{
    __shared__ __hip_bfloat16 Kl[BK * KSTR];
    __shared__ __hip_bfloat16 Vt[D_DIM * KSTR];
    __shared__ __hip_bfloat16 Pl[4][16 * KSTR];

    const int tid  = threadIdx.x;
    const int wave = tid >> 6;
    const int idx  = blockIdx.x;
    const int bh   = idx & (BH - 1);
    const int qt   = (NQT - 1) - (idx >> 5);
    const int q0   = qt * BQ;

    const size_t bqd = (size_t)bh * S_LEN * D_DIM;
    float* Ob = Out + bqd;
    float* Wb = W + (size_t)bh * S_LEN * S_LEN;

    const unsigned int sw = *(const unsigned int*)scp;
    const bool isf32 = ((sw & 0xFFFFu) == 0u);
    const float sc = isf32 ? __builtin_bit_cast(float, sw)
                           : __builtin_bit_cast(float, (sw & 0xFFFFu) << 16);
    const float sc2 = sc * 1.44269504088896f;

    {
        const int zc = S_LEN - (q0 + BQ);
        floatx4 z4 = {0.f, 0.f, 0.f, 0.f};
        for (int r = 0; r < BQ; ++r) {
            float* wr = Wb + (size_t)(q0 + r) * S_LEN + (q0 + BQ);
            for (int c = tid * 4; c < zc; c += 256 * 4)
                *(floatx4*)(wr + c) = z4;
        }
    }

    if (isf32)
        attn_body<float>((const float*)Q + bqd, (const float*)K + bqd,
                         (const float*)V + bqd, sc2, Ob, Wb, q0, qt, Kl, Vt, Pl[wave]);
    else
        attn_body<__hip_bfloat16>((const __hip_bfloat16*)Q + bqd, (const __hip_bfloat16*)K + bqd,
                                  (const __hip_bfloat16*)V + bqd, sc2, Ob, Wb, q0, qt, Kl, Vt, Pl[wave]);
}

extern "C" void kernel_launch(void* const* d_in, const int* in_sizes, int n_in,
                              void* d_out, int out_size, void* d_ws, size_t ws_size,
                              hipStream_t stream) {
    float* Outp = (float*)d_out;                           // [B,H,S,D] fp32
    float* Wp   = Outp + NEL;                              // [B,H,S,S] fp32

    const size_t need = NEL * 3 * sizeof(unsigned short);  // 25.2 MB bf16 Q,K,V^T
    if (d_ws != nullptr && ws_size >= need) {
        unsigned short* Qb  = (unsigned short*)d_ws;
        unsigned short* Kb  = Qb + NEL;
        unsigned short* Vtg = Kb + NEL;
        prep_kernel<<<dim3(NQT * BH), dim3(256), 0, stream>>>(
            d_in[0], d_in[1], d_in[2], d_in[3], Qb, Kb, Vtg);
        attn_fast<<<dim3(NQT * BH), dim3(256), 0, stream>>>(
            Qb, Kb, Vtg, d_in[3], Outp, Wp);
    } else {
        attn_kernel<<<dim3(NQT * BH), dim3(256), 0, stream>>>(
            d_in[0], d_in[1], d_in[2], d_in[3], Outp, Wp);
    }
}

// Round 3
// 679.162 us; speedup vs baseline: 1.0829x; 1.0829x over previous
//
#include <hip/hip_runtime.h>
#include <hip/hip_bf16.h>

#define S_LEN 2048
#define D_DIM 64
#define BH    32          // B*H
#define BQ    64          // queries per block (4 waves x 16 rows)
#define BK    64          // keys per k-tile
#define NQT   (S_LEN/BQ)  // 32
#define KSTR  72          // padded LDS stride (bf16 elems) to break bank conflicts
#define NEL   ((size_t)BH * S_LEN * D_DIM)   // 4,194,304 elems per tensor

typedef __attribute__((ext_vector_type(4))) short  short4v;  // 4 bf16 = 8B
typedef __attribute__((ext_vector_type(8))) short  short8;   // 8 bf16 = 16B (MFMA frag)
typedef __attribute__((ext_vector_type(4))) float  floatx4;
typedef __attribute__((ext_vector_type(4))) unsigned int uintx4;

__device__ __forceinline__ unsigned short f2bf(float f) {   // RNE fp32->bf16
    unsigned int u = __builtin_bit_cast(unsigned int, f);
    u += 0x7FFFu + ((u >> 16) & 1u);
    return (unsigned short)(u >> 16);
}
__device__ __forceinline__ float bf2f(short s) {            // bf16 bits -> fp32
    return __builtin_bit_cast(float, ((unsigned int)(unsigned short)s) << 16);
}

// ---- dtype-generic 8-element row loads producing bf16 fragments ----
__device__ __forceinline__ short8 load8(const float* p) {
    floatx4 a = *(const floatx4*)p;
    floatx4 b = *(const floatx4*)(p + 4);
    short8 r;
    r[0]=(short)f2bf(a[0]); r[1]=(short)f2bf(a[1]); r[2]=(short)f2bf(a[2]); r[3]=(short)f2bf(a[3]);
    r[4]=(short)f2bf(b[0]); r[5]=(short)f2bf(b[1]); r[6]=(short)f2bf(b[2]); r[7]=(short)f2bf(b[3]);
    return r;
}
__device__ __forceinline__ short8 load8(const __hip_bfloat16* p) {
    return *(const short8*)p;
}
__device__ __forceinline__ void loadrow8(const float* p, unsigned short o[8]) {
    floatx4 a = *(const floatx4*)p, b = *(const floatx4*)(p + 4);
    o[0]=f2bf(a[0]); o[1]=f2bf(a[1]); o[2]=f2bf(a[2]); o[3]=f2bf(a[3]);
    o[4]=f2bf(b[0]); o[5]=f2bf(b[1]); o[6]=f2bf(b[2]); o[7]=f2bf(b[3]);
}
__device__ __forceinline__ void loadrow8(const __hip_bfloat16* p, unsigned short o[8]) {
    short8 v = *(const short8*)p;
#pragma unroll
    for (int j = 0; j < 8; ++j) o[j] = (unsigned short)v[j];
}

// ============================================================================
// PREP KERNEL: one-time Q,K -> bf16 and V -> V^T bf16 into workspace.
// ============================================================================
template<typename TIN>
__device__ __forceinline__ void prep_body(const TIN* __restrict__ Q, const TIN* __restrict__ K,
                                          const TIN* __restrict__ V,
                                          unsigned short* __restrict__ Qb,
                                          unsigned short* __restrict__ Kb,
                                          unsigned short* __restrict__ Vtg,
                                          unsigned short (*Lt)[KSTR])
{
    const int tid = threadIdx.x;
    const int bid = blockIdx.x;
    {   // Q/K straight conversion, 16 elems per thread each
        size_t idx = ((size_t)bid * 256 + tid) * 16;
        *(short8*)(Qb + idx)     = load8(Q + idx);
        *(short8*)(Qb + idx + 8) = load8(Q + idx + 8);
        *(short8*)(Kb + idx)     = load8(K + idx);
        *(short8*)(Kb + idx + 8) = load8(K + idx + 8);
    }
    const int bh = bid >> 5, st = bid & 31;
    const TIN* Vb = V + ((size_t)bh * S_LEN + (size_t)st * 64) * D_DIM;
#pragma unroll
    for (int i = 0; i < 2; ++i) {                 // load V tile -> LDS (bf16)
        int flat = tid * 8 + i * 2048;
        int r = flat >> 6, c = flat & 63;
        short8 v = load8(Vb + (size_t)r * D_DIM + c);
        *(short8*)(&Lt[r][c]) = v;
    }
    __syncthreads();
    unsigned short* Vh = Vtg + (size_t)bh * D_DIM * S_LEN;
#pragma unroll
    for (int i = 0; i < 4; ++i) {                 // transposed coalesced write
        int flat = tid * 4 + i * 1024;
        int d = flat >> 6, sj = flat & 63;        // sj multiple of 4
        short4v o;
        o[0] = (short)Lt[sj+0][d]; o[1] = (short)Lt[sj+1][d];
        o[2] = (short)Lt[sj+2][d]; o[3] = (short)Lt[sj+3][d];
        *(short4v*)(Vh + (size_t)d * S_LEN + (size_t)st * 64 + sj) = o;
    }
}

__global__ __launch_bounds__(256)
void prep_kernel(const void* __restrict__ Q, const void* __restrict__ K,
                 const void* __restrict__ V, const void* __restrict__ scp,
                 unsigned short* __restrict__ Qb, unsigned short* __restrict__ Kb,
                 unsigned short* __restrict__ Vtg)
{
    __shared__ unsigned short Lt[64][KSTR];
    const unsigned int sw = *(const unsigned int*)scp;
    if ((sw & 0xFFFFu) == 0u)
        prep_body<float>((const float*)Q, (const float*)K, (const float*)V, Qb, Kb, Vtg, Lt);
    else
        prep_body<__hip_bfloat16>((const __hip_bfloat16*)Q, (const __hip_bfloat16*)K,
                                  (const __hip_bfloat16*)V, Qb, Kb, Vtg, Lt);
}

// ============================================================================
// FAST ATTENTION KERNEL (bf16 pre-staged inputs)
// ============================================================================
__device__ __forceinline__ void ldK(const unsigned short* Kh, int kk0, int tid, uintx4 r[2]) {
#pragma unroll
    for (int i = 0; i < 2; ++i)
        r[i] = *(const uintx4*)(Kh + (size_t)kk0 * D_DIM + tid * 8 + i * 2048);
}
__device__ __forceinline__ void ldV(const unsigned short* Vh, int kk0, int tid, uintx4 r[2]) {
#pragma unroll
    for (int i = 0; i < 2; ++i) {
        int flat = tid * 8 + i * 2048;
        r[i] = *(const uintx4*)(Vh + (size_t)(flat >> 6) * S_LEN + kk0 + (flat & 63));
    }
}
__device__ __forceinline__ void st2(unsigned short* dst, int tid, const uintx4 r[2]) {
#pragma unroll
    for (int i = 0; i < 2; ++i) {
        int flat = tid * 8 + i * 2048;
        *(uintx4*)(dst + (flat >> 6) * KSTR + (flat & 63)) = r[i];
    }
}

__global__ __launch_bounds__(256, 4)
void attn_fast(const unsigned short* __restrict__ Qb, const unsigned short* __restrict__ Kb,
               const unsigned short* __restrict__ Vtg, const void* __restrict__ scp,
               float* __restrict__ Out, float* __restrict__ W)
{
    __shared__ unsigned short Kl[2][BK * KSTR];   // double-buffered K
    __shared__ unsigned short Vl[2][D_DIM * KSTR];// double-buffered V^T

    const int tid  = threadIdx.x;
    const int wave = tid >> 6;
    const int lane = tid & 63;
    const int quad = lane >> 4;
    const int lm   = lane & 15;
    const int idx  = blockIdx.x;
    const int bh   = idx & (BH - 1);
    const int qt   = (NQT - 1) - (idx >> 5);   // heavy causal tiles dispatched first
    const int q0   = qt * BQ;

    const unsigned int sw = *(const unsigned int*)scp;
    const bool isf32 = ((sw & 0xFFFFu) == 0u);
    const float sc = isf32 ? __builtin_bit_cast(float, sw)
                           : __builtin_bit_cast(float, (sw & 0xFFFFu) << 16);
    const float sc2 = sc * 1.44269504088896f;   // base-2 softmax

    float* Ob = Out + (size_t)bh * S_LEN * D_DIM;
    float* Wb = W   + (size_t)bh * S_LEN * S_LEN;
    const unsigned short* Qh = Qb  + (size_t)bh * S_LEN * D_DIM;
    const unsigned short* Kh = Kb  + (size_t)bh * S_LEN * D_DIM;
    const unsigned short* Vh = Vtg + (size_t)bh * D_DIM * S_LEN;

    // zero-fill masked weights region (write-only -> nontemporal)
    {
        const int zc = S_LEN - (q0 + BQ);
        floatx4 z4 = {0.f, 0.f, 0.f, 0.f};
        for (int r = 0; r < BQ; ++r) {
            float* wr = Wb + (size_t)(q0 + r) * S_LEN + (q0 + BQ);
            for (int c = tid * 4; c < zc; c += 256 * 4)
                __builtin_nontemporal_store(z4, (floatx4*)(wr + c));
        }
    }

    // Q fragments, resident all kernel
    const int qrow = q0 + wave * 16 + lm;
    const short8 qf0 = *(const short8*)(Qh + (size_t)qrow * D_DIM + quad * 8);
    const short8 qf1 = *(const short8*)(Qh + (size_t)qrow * D_DIM + 32 + quad * 8);

    // =========== PASS 1: row sums (no max -- |s*log2e| small, exp2 safe) ===========
    // Swapped MFMA: C[k][q] -> lane holds k-values of q-row q=lm.
    {
        uintx4 kr[2];
        ldK(Kh, 0, tid, kr); st2(Kl[0], tid, kr);
    }
    __syncthreads();

    float ls0 = 0.f, ls1 = 0.f, ls2 = 0.f, ls3 = 0.f;
    for (int kt = 0; kt <= qt; ++kt) {
        const bool pre = (kt < qt);
        uintx4 kreg[2];
        if (pre) ldK(Kh, (kt + 1) * BK, tid, kreg);       // T14: issue early
        const unsigned short* Kc = Kl[kt & 1];
        const int kk0 = kt * BK;
        const bool diag = (kt == qt);
#pragma unroll
        for (int kkt = 0; kkt < 4; ++kkt) {
            floatx4 acc = {0.f, 0.f, 0.f, 0.f};
            short8 b0 = *(const short8*)(Kc + (kkt * 16 + lm) * KSTR + quad * 8);
            short8 b1 = *(const short8*)(Kc + (kkt * 16 + lm) * KSTR + 32 + quad * 8);
            acc = __builtin_amdgcn_mfma_f32_16x16x32_bf16(b0, qf0, acc, 0, 0, 0);
            acc = __builtin_amdgcn_mfma_f32_16x16x32_bf16(b1, qf1, acc, 0, 0, 0);
            float s0 = acc[0] * sc2, s1 = acc[1] * sc2;
            float s2 = acc[2] * sc2, s3 = acc[3] * sc2;
            if (diag) {
                int kg = kk0 + kkt * 16 + quad * 4;        // k-global of acc[0]
                if (kg + 0 > qrow) s0 = -1e30f;
                if (kg + 1 > qrow) s1 = -1e30f;
                if (kg + 2 > qrow) s2 = -1e30f;
                if (kg + 3 > qrow) s3 = -1e30f;
            }
            ls0 += exp2f(s0); ls1 += exp2f(s1);
            ls2 += exp2f(s2); ls3 += exp2f(s3);
        }
        if (pre) st2(Kl[(kt + 1) & 1], tid, kreg);        // T14: write late
        __syncthreads();
    }
    float lsum = (ls0 + ls1) + (ls2 + ls3);
    lsum += __shfl_xor(lsum, 16, 64);
    lsum += __shfl_xor(lsum, 32, 64);
    const float linv = 1.0f / lsum;       // row sum for q = lm (uniform over quads)

    // ===== PASS 2: swapped-score recompute, W from regs, PV via permlane transpose =====
    {
        uintx4 kr[2], vr[2];
        ldK(Kh, 0, tid, kr); ldV(Vh, 0, tid, vr);
        st2(Kl[0], tid, kr); st2(Vl[0], tid, vr);
    }
    __syncthreads();

    floatx4 oacc[4];
#pragma unroll
    for (int dt = 0; dt < 4; ++dt) oacc[dt] = (floatx4){0.f, 0.f, 0.f, 0.f};

    for (int kt = 0; kt <= qt; ++kt) {
        const bool pre = (kt < qt);
        uintx4 kreg[2], vreg[2];
        if (pre) { ldK(Kh, (kt + 1) * BK, tid, kreg); ldV(Vh, (kt + 1) * BK, tid, vreg); }
        const unsigned short* Kc = Kl[kt & 1];
        const unsigned short* Vc = Vl[kt & 1];
        const int kk0 = kt * BK;
        const bool diag = (kt == qt);

        unsigned int dd[4][2];                            // bf16 P pairs, pre-transpose
#pragma unroll
        for (int kkt = 0; kkt < 4; ++kkt) {               // swapped scores: lane q = lm
            floatx4 acc = {0.f, 0.f, 0.f, 0.f};
            short8 b0 = *(const short8*)(Kc + (kkt * 16 + lm) * KSTR + quad * 8);
            short8 b1 = *(const short8*)(Kc + (kkt * 16 + lm) * KSTR + 32 + quad * 8);
            acc = __builtin_amdgcn_mfma_f32_16x16x32_bf16(b0, qf0, acc, 0, 0, 0);
            acc = __builtin_amdgcn_mfma_f32_16x16x32_bf16(b1, qf1, acc, 0, 0, 0);
            const int kg = kk0 + kkt * 16 + quad * 4;     // k of acc[0]
            float s0 = acc[0] * sc2, s1 = acc[1] * sc2;
            float s2 = acc[2] * sc2, s3 = acc[3] * sc2;
            if (diag) {
                if (kg + 0 > qrow) s0 = -1e30f;
                if (kg + 1 > qrow) s1 = -1e30f;
                if (kg + 2 > qrow) s2 = -1e30f;
                if (kg + 3 > qrow) s3 = -1e30f;
            }
            float p0 = exp2f(s0) * linv, p1 = exp2f(s1) * linv;
            float p2 = exp2f(s2) * linv, p3 = exp2f(s3) * linv;
            // W store straight from registers: row qrow, 4 consecutive cols at kg
            floatx4 w4; w4[0] = p0; w4[1] = p1; w4[2] = p2; w4[3] = p3;
            __builtin_nontemporal_store(w4, (floatx4*)(Wb + (size_t)qrow * S_LEN + kg));
            // pack to bf16 pairs (lo = even k, hi = odd k)
            asm("v_cvt_pk_bf16_f32 %0, %1, %2" : "=v"(dd[kkt][0]) : "v"(p0), "v"(p1));
            asm("v_cvt_pk_bf16_f32 %0, %1, %2" : "=v"(dd[kkt][1]) : "v"(p2), "v"(p3));
        }
        // 4x4 quad transpose in-register: rotation (b5,b4,t) -> (t,b5,b4) =
        // swap(b5,t) then swap(b4,t), each with vdst = t=0 reg (dd[2c]),
        // vsrc = t=1 reg (dd[2c+1]):
        //   permlane32_swap(X,Y): X.rows23 <-> Y.rows01  == bitswap(lane5, reg)
        //   permlane16_swap(X,Y): X.odd rows <-> Y.even  == bitswap(lane4, reg)
        // Verified by element trace: (t,qs,u)=(1,1,1)->quad2/w3, (0,2,0)->quad1/w0,
        // (0,1,0)->quad0/w2, (0,0,0) fixed point.
#pragma unroll
        for (int c = 0; c < 2; ++c) {
            asm("v_permlane32_swap_b32 %0, %1" : "+v"(dd[2*c][0]), "+v"(dd[2*c+1][0]));
            asm("v_permlane32_swap_b32 %0, %1" : "+v"(dd[2*c][1]), "+v"(dd[2*c+1][1]));
            asm("v_permlane16_swap_b32 %0, %1" : "+v"(dd[2*c][0]), "+v"(dd[2*c+1][0]));
            asm("v_permlane16_swap_b32 %0, %1" : "+v"(dd[2*c][1]), "+v"(dd[2*c+1][1]));
        }
#pragma unroll
        for (int c = 0; c < 2; ++c) {                     // O += P * V
            uintx4 pv_;
            pv_[0] = dd[2*c][0]; pv_[1] = dd[2*c][1];
            pv_[2] = dd[2*c+1][0]; pv_[3] = dd[2*c+1][1];
            short8 pf = __builtin_bit_cast(short8, pv_);
#pragma unroll
            for (int dt = 0; dt < 4; ++dt) {
                short8 vf = *(const short8*)(Vc + (dt * 16 + lm) * KSTR + c * 32 + quad * 8);
                oacc[dt] = __builtin_amdgcn_mfma_f32_16x16x32_bf16(pf, vf, oacc[dt], 0, 0, 0);
            }
        }

        if (pre) {
            st2(Kl[(kt + 1) & 1], tid, kreg);   // other buffers: nobody reads them now
            st2(Vl[(kt + 1) & 1], tid, vreg);
            __syncthreads();                    // single barrier per tile
        }
    }

    // ---- epilogue: O stored fp32 directly from accumulators (C-layout) ----
#pragma unroll
    for (int dt = 0; dt < 4; ++dt)
#pragma unroll
        for (int r = 0; r < 4; ++r)
            Ob[(size_t)(q0 + wave * 16 + quad * 4 + r) * D_DIM + dt * 16 + lm] = oacc[dt][r];
}

// ============================================================================
// FALLBACK (verified R0 kernel) -- used only if ws_size is too small
// ============================================================================
template<typename TIN>
__device__ __forceinline__ void stageK(const TIN* Kb, int kk0, __hip_bfloat16* Kl, int tid) {
    if constexpr (sizeof(TIN) == 4) {
#pragma unroll
        for (int i = 0; i < 4; ++i) {
            int flat = tid * 4 + i * 1024;
            int row = flat >> 6, col = flat & 63;
            floatx4 v = *(const floatx4*)((const float*)Kb + (size_t)(kk0 + row) * D_DIM + col);
            short4v s;
            s[0]=(short)f2bf(v[0]); s[1]=(short)f2bf(v[1]);
            s[2]=(short)f2bf(v[2]); s[3]=(short)f2bf(v[3]);
            *(short4v*)(&Kl[row * KSTR + col]) = s;
        }
    } else {
#pragma unroll
        for (int i = 0; i < 2; ++i) {
            int flat = tid * 8 + i * 2048;
            int row = flat >> 6, col = flat & 63;
            *(uintx4*)(&Kl[row * KSTR + col]) =
                *(const uintx4*)((const __hip_bfloat16*)Kb + (size_t)(kk0 + row) * D_DIM + col);
        }
    }
}

template<typename TIN>
__device__ __forceinline__ void attn_body(
    const TIN* __restrict__ Qb, const TIN* __restrict__ Kb, const TIN* __restrict__ Vb,
    float sc2, float* __restrict__ Ob, float* __restrict__ Wb,
    int q0, int qt, __hip_bfloat16* Kl, __hip_bfloat16* Vt, __hip_bfloat16* Plw)
{
    const int tid  = threadIdx.x;
    const int wave = tid >> 6;
    const int lane = tid & 63;
    const int quad = lane >> 4;
    const int lm   = lane & 15;

    const int qrow = q0 + wave * 16 + lm;
    short8 qfrag0 = load8(Qb + (size_t)qrow * D_DIM + quad * 8);
    short8 qfrag1 = load8(Qb + (size_t)qrow * D_DIM + 32 + quad * 8);

    float mrow[4], lrow[4];
#pragma unroll
    for (int r = 0; r < 4; ++r) { mrow[r] = -1e30f; lrow[r] = 0.f; }

    for (int kt = 0; kt <= qt; ++kt) {
        const int kk0 = kt * BK;
        __syncthreads();
        stageK(Kb, kk0, Kl, tid);
        __syncthreads();

        const bool diag = (kt == qt);
        float s[4][4];
#pragma unroll
        for (int kkt = 0; kkt < 4; ++kkt) {
            floatx4 acc = {0.f, 0.f, 0.f, 0.f};
            short8 b0 = *(const short8*)(&Kl[(kkt * 16 + lm) * KSTR + quad * 8]);
            short8 b1 = *(const short8*)(&Kl[(kkt * 16 + lm) * KSTR + 32 + quad * 8]);
            acc = __builtin_amdgcn_mfma_f32_16x16x32_bf16(qfrag0, b0, acc, 0, 0, 0);
            acc = __builtin_amdgcn_mfma_f32_16x16x32_bf16(qfrag1, b1, acc, 0, 0, 0);
#pragma unroll
            for (int r = 0; r < 4; ++r) s[kkt][r] = acc[r] * sc2;
            if (diag) {
                int colg = kk0 + kkt * 16 + lm;
#pragma unroll
                for (int r = 0; r < 4; ++r) {
                    int rowg = q0 + wave * 16 + quad * 4 + r;
                    if (colg > rowg) s[kkt][r] = -1e30f;
                }
            }
        }
#pragma unroll
        for (int r = 0; r < 4; ++r) {
            float mx = fmaxf(fmaxf(s[0][r], s[1][r]), fmaxf(s[2][r], s[3][r]));
#pragma unroll
            for (int off = 1; off < 16; off <<= 1)
                mx = fmaxf(mx, __shfl_xor(mx, off, 64));
            float mnew = fmaxf(mrow[r], mx);
            float p = exp2f(s[0][r] - mnew) + exp2f(s[1][r] - mnew) +
                      exp2f(s[2][r] - mnew) + exp2f(s[3][r] - mnew);
#pragma unroll
            for (int off = 1; off < 16; off <<= 1)
                p += __shfl_xor(p, off, 64);
            lrow[r] = lrow[r] * exp2f(mrow[r] - mnew) + p;
            mrow[r] = mnew;
        }
    }

    float inv_l[4];
#pragma unroll
    for (int r = 0; r < 4; ++r) inv_l[r] = 1.0f / lrow[r];

    floatx4 oacc[4];
#pragma unroll
    for (int dt = 0; dt < 4; ++dt) oacc[dt] = (floatx4){0.f, 0.f, 0.f, 0.f};

    for (int kt = 0; kt <= qt; ++kt) {
        const int kk0 = kt * BK;
        __syncthreads();
        stageK(Kb, kk0, Kl, tid);
        {
            int r = tid & 31, c = (tid >> 5) << 3;
            const TIN* v0 = Vb + (size_t)(kk0 + 2 * r) * D_DIM + c;
            unsigned short a[8], b[8];
            loadrow8(v0, a);
            loadrow8(v0 + D_DIM, b);
#pragma unroll
            for (int j = 0; j < 8; ++j) {
                unsigned int d = (unsigned int)a[j] | ((unsigned int)b[j] << 16);
                *(unsigned int*)(&Vt[(c + j) * KSTR + 2 * r]) = d;
            }
        }
        __syncthreads();

        const bool diag = (kt == qt);
        float s[4][4];
#pragma unroll
        for (int kkt = 0; kkt < 4; ++kkt) {
            floatx4 acc = {0.f, 0.f, 0.f, 0.f};
            short8 b0 = *(const short8*)(&Kl[(kkt * 16 + lm) * KSTR + quad * 8]);
            short8 b1 = *(const short8*)(&Kl[(kkt * 16 + lm) * KSTR + 32 + quad * 8]);
            acc = __builtin_amdgcn_mfma_f32_16x16x32_bf16(qfrag0, b0, acc, 0, 0, 0);
            acc = __builtin_amdgcn_mfma_f32_16x16x32_bf16(qfrag1, b1, acc, 0, 0, 0);
#pragma unroll
            for (int r = 0; r < 4; ++r) s[kkt][r] = acc[r] * sc2;
            if (diag) {
                int colg = kk0 + kkt * 16 + lm;
#pragma unroll
                for (int r = 0; r < 4; ++r) {
                    int rowg = q0 + wave * 16 + quad * 4 + r;
                    if (colg > rowg) s[kkt][r] = -1e30f;
                }
            }
        }
#pragma unroll
        for (int kkt = 0; kkt < 4; ++kkt) {
#pragma unroll
            for (int r = 0; r < 4; ++r) {
                float p = exp2f(s[kkt][r] - mrow[r]) * inv_l[r];
                Plw[(quad * 4 + r) * KSTR + kkt * 16 + lm] =
                    __builtin_bit_cast(__hip_bfloat16, f2bf(p));
            }
        }
        __asm__ volatile("s_waitcnt lgkmcnt(0)" ::: "memory");

        {
            int rr = lane >> 3, cc = (lane & 7) << 3;
            short8 w0 = *(const short8*)(&Plw[rr * KSTR + cc]);
            short8 w1 = *(const short8*)(&Plw[(8 + rr) * KSTR + cc]);
            float* wp0 = Wb + (size_t)(q0 + wave * 16 + rr) * S_LEN + kk0 + cc;
            float* wp1 = Wb + (size_t)(q0 + wave * 16 + 8 + rr) * S_LEN + kk0 + cc;
            floatx4 fa, fb;
#pragma unroll
            for (int j = 0; j < 4; ++j) { fa[j] = bf2f(w0[j]); fb[j] = bf2f(w0[4 + j]); }
            *(floatx4*)wp0 = fa; *(floatx4*)(wp0 + 4) = fb;
#pragma unroll
            for (int j = 0; j < 4; ++j) { fa[j] = bf2f(w1[j]); fb[j] = bf2f(w1[4 + j]); }
            *(floatx4*)wp1 = fa; *(floatx4*)(wp1 + 4) = fb;
        }
#pragma unroll
        for (int c = 0; c < 2; ++c) {
            short8 pf = *(const short8*)(&Plw[lm * KSTR + c * 32 + quad * 8]);
#pragma unroll
            for (int dt = 0; dt < 4; ++dt) {
                short8 vf = *(const short8*)(&Vt[(dt * 16 + lm) * KSTR + c * 32 + quad * 8]);
                oacc[dt] = __builtin_amdgcn_mfma_f32_16x16x32_bf16(pf, vf, oacc[dt], 0, 0, 0);
            }
        }
    }

#pragma unroll
    for (int dt = 0; dt < 4; ++dt)
#pragma unroll
        for (int r = 0; r < 4; ++r)
            Ob[(size_t)(q0 + wave * 16 + quad * 4 + r) * D_DIM + dt * 16 + lm] = oacc[dt][r];
}

__global__ __launch_bounds__(256, 4)
void attn_kernel(const void* __restrict__ Q, const void* __restrict__ K,
                 const void* __restrict__ V, const void* __restrict__ scp,
                 float* __restrict__ Out, float* __restrict__ W)
{
    __shared__ __hip_bfloat16 Kl[BK * KSTR];
    __shared__ __hip_bfloat16 Vt[D_DIM * KSTR];
    __shared__ __hip_bfloat16 Pl[4][16 * KSTR];

    const int tid  = threadIdx.x;
    const int wave = tid >> 6;
    const int idx  = blockIdx.x;
    const int bh   = idx & (BH - 1);
    const int qt   = (NQT - 1) - (idx >> 5);
    const int q0   = qt * BQ;

    const size_t bqd = (size_t)bh * S_LEN * D_DIM;
    float* Ob = Out + bqd;
    float* Wb = W + (size_t)bh * S_LEN * S_LEN;

    const unsigned int sw = *(const unsigned int*)scp;
    const bool isf32 = ((sw & 0xFFFFu) == 0u);
    const float sc = isf32 ? __builtin_bit_cast(float, sw)
                           : __builtin_bit_cast(float, (sw & 0xFFFFu) << 16);
    const float sc2 = sc * 1.44269504088896f;

    {
        const int zc = S_LEN - (q0 + BQ);
        floatx4 z4 = {0.f, 0.f, 0.f, 0.f};
        for (int r = 0; r < BQ; ++r) {
            float* wr = Wb + (size_t)(q0 + r) * S_LEN + (q0 + BQ);
            for (int c = tid * 4; c < zc; c += 256 * 4)
                *(floatx4*)(wr + c) = z4;
        }
    }

    if (isf32)
        attn_body<float>((const float*)Q + bqd, (const float*)K + bqd,
                         (const float*)V + bqd, sc2, Ob, Wb, q0, qt, Kl, Vt, Pl[wave]);
    else
        attn_body<__hip_bfloat16>((const __hip_bfloat16*)Q + bqd, (const __hip_bfloat16*)K + bqd,
                                  (const __hip_bfloat16*)V + bqd, sc2, Ob, Wb, q0, qt, Kl, Vt, Pl[wave]);
}

extern "C" void kernel_launch(void* const* d_in, const int* in_sizes, int n_in,
                              void* d_out, int out_size, void* d_ws, size_t ws_size,
                              hipStream_t stream) {
    float* Outp = (float*)d_out;                           // [B,H,S,D] fp32
    float* Wp   = Outp + NEL;                              // [B,H,S,S] fp32

    const size_t need = NEL * 3 * sizeof(unsigned short);  // 25.2 MB bf16 Q,K,V^T
    if (d_ws != nullptr && ws_size >= need) {
        unsigned short* Qb  = (unsigned short*)d_ws;
        unsigned short* Kb  = Qb + NEL;
        unsigned short* Vtg = Kb + NEL;
        prep_kernel<<<dim3(NQT * BH), dim3(256), 0, stream>>>(
            d_in[0], d_in[1], d_in[2], d_in[3], Qb, Kb, Vtg);
        attn_fast<<<dim3(NQT * BH), dim3(256), 0, stream>>>(
            Qb, Kb, Vtg, d_in[3], Outp, Wp);
    } else {
        attn_kernel<<<dim3(NQT * BH), dim3(256), 0, stream>>>(
            d_in[0], d_in[1], d_in[2], d_in[3], Outp, Wp);
    }
}

// Round 4
// 659.408 us; speedup vs baseline: 1.1153x; 1.0300x over previous
//
#include <hip/hip_runtime.h>
#include <hip/hip_bf16.h>

#define S_LEN 2048
#define D_DIM 64
#define BH    32          // B*H
#define BQ    64          // queries per q-tile (4 waves x 16 rows)
#define BK    64          // keys per k-tile
#define NQT   (S_LEN/BQ)  // 32
#define NPAIR (NQT/2)     // 16 balanced q-tile pairs
#define KSTR  72          // padded LDS stride (bf16 elems) to break bank conflicts
#define NEL   ((size_t)BH * S_LEN * D_DIM)   // 4,194,304 elems per tensor

typedef __attribute__((ext_vector_type(4))) short  short4v;  // 4 bf16 = 8B
typedef __attribute__((ext_vector_type(8))) short  short8;   // 8 bf16 = 16B (MFMA frag)
typedef __attribute__((ext_vector_type(4))) float  floatx4;
typedef __attribute__((ext_vector_type(4))) unsigned int uintx4;

__device__ __forceinline__ unsigned short f2bf(float f) {   // RNE fp32->bf16
    unsigned int u = __builtin_bit_cast(unsigned int, f);
    u += 0x7FFFu + ((u >> 16) & 1u);
    return (unsigned short)(u >> 16);
}
__device__ __forceinline__ float bf2f(short s) {            // bf16 bits -> fp32
    return __builtin_bit_cast(float, ((unsigned int)(unsigned short)s) << 16);
}

// ---- dtype-generic 8-element row loads producing bf16 fragments ----
__device__ __forceinline__ short8 load8(const float* p) {
    floatx4 a = *(const floatx4*)p;
    floatx4 b = *(const floatx4*)(p + 4);
    short8 r;
    r[0]=(short)f2bf(a[0]); r[1]=(short)f2bf(a[1]); r[2]=(short)f2bf(a[2]); r[3]=(short)f2bf(a[3]);
    r[4]=(short)f2bf(b[0]); r[5]=(short)f2bf(b[1]); r[6]=(short)f2bf(b[2]); r[7]=(short)f2bf(b[3]);
    return r;
}
__device__ __forceinline__ short8 load8(const __hip_bfloat16* p) {
    return *(const short8*)p;
}
__device__ __forceinline__ void loadrow8(const float* p, unsigned short o[8]) {
    floatx4 a = *(const floatx4*)p, b = *(const floatx4*)(p + 4);
    o[0]=f2bf(a[0]); o[1]=f2bf(a[1]); o[2]=f2bf(a[2]); o[3]=f2bf(a[3]);
    o[4]=f2bf(b[0]); o[5]=f2bf(b[1]); o[6]=f2bf(b[2]); o[7]=f2bf(b[3]);
}
__device__ __forceinline__ void loadrow8(const __hip_bfloat16* p, unsigned short o[8]) {
    short8 v = *(const short8*)p;
#pragma unroll
    for (int j = 0; j < 8; ++j) o[j] = (unsigned short)v[j];
}

// ============================================================================
// PREP KERNEL: one-time Q,K -> bf16 and V -> V^T bf16 into workspace.
// Grid = NQT*BH = 1024 blocks (exact slice coverage of NEL).
// ============================================================================
template<typename TIN>
__device__ __forceinline__ void prep_body(const TIN* __restrict__ Q, const TIN* __restrict__ K,
                                          const TIN* __restrict__ V,
                                          unsigned short* __restrict__ Qb,
                                          unsigned short* __restrict__ Kb,
                                          unsigned short* __restrict__ Vtg,
                                          unsigned short (*Lt)[KSTR])
{
    const int tid = threadIdx.x;
    const int bid = blockIdx.x;
    {   // Q/K straight conversion, 16 elems per thread each
        size_t idx = ((size_t)bid * 256 + tid) * 16;
        *(short8*)(Qb + idx)     = load8(Q + idx);
        *(short8*)(Qb + idx + 8) = load8(Q + idx + 8);
        *(short8*)(Kb + idx)     = load8(K + idx);
        *(short8*)(Kb + idx + 8) = load8(K + idx + 8);
    }
    const int bh = bid >> 5, st = bid & 31;
    const TIN* Vb = V + ((size_t)bh * S_LEN + (size_t)st * 64) * D_DIM;
#pragma unroll
    for (int i = 0; i < 2; ++i) {                 // load V tile -> LDS (bf16)
        int flat = tid * 8 + i * 2048;
        int r = flat >> 6, c = flat & 63;
        short8 v = load8(Vb + (size_t)r * D_DIM + c);
        *(short8*)(&Lt[r][c]) = v;
    }
    __syncthreads();
    unsigned short* Vh = Vtg + (size_t)bh * D_DIM * S_LEN;
#pragma unroll
    for (int i = 0; i < 4; ++i) {                 // transposed coalesced write
        int flat = tid * 4 + i * 1024;
        int d = flat >> 6, sj = flat & 63;        // sj multiple of 4
        short4v o;
        o[0] = (short)Lt[sj+0][d]; o[1] = (short)Lt[sj+1][d];
        o[2] = (short)Lt[sj+2][d]; o[3] = (short)Lt[sj+3][d];
        *(short4v*)(Vh + (size_t)d * S_LEN + (size_t)st * 64 + sj) = o;
    }
}

__global__ __launch_bounds__(256)
void prep_kernel(const void* __restrict__ Q, const void* __restrict__ K,
                 const void* __restrict__ V, const void* __restrict__ scp,
                 unsigned short* __restrict__ Qb, unsigned short* __restrict__ Kb,
                 unsigned short* __restrict__ Vtg)
{
    __shared__ unsigned short Lt[64][KSTR];
    const unsigned int sw = *(const unsigned int*)scp;
    if ((sw & 0xFFFFu) == 0u)
        prep_body<float>((const float*)Q, (const float*)K, (const float*)V, Qb, Kb, Vtg, Lt);
    else
        prep_body<__hip_bfloat16>((const __hip_bfloat16*)Q, (const __hip_bfloat16*)K,
                                  (const __hip_bfloat16*)V, Qb, Kb, Vtg, Lt);
}

// ============================================================================
// JOINT ATTENTION KERNEL: one block = balanced q-tile pair (j, 31-j).
// All K/V staging, barriers and LDS fragment reads shared by both q-tiles.
// ============================================================================
__device__ __forceinline__ void ldK(const unsigned short* Kh, int kk0, int tid, uintx4 r[2]) {
#pragma unroll
    for (int i = 0; i < 2; ++i)
        r[i] = *(const uintx4*)(Kh + (size_t)kk0 * D_DIM + tid * 8 + i * 2048);
}
__device__ __forceinline__ void ldV(const unsigned short* Vh, int kk0, int tid, uintx4 r[2]) {
#pragma unroll
    for (int i = 0; i < 2; ++i) {
        int flat = tid * 8 + i * 2048;
        r[i] = *(const uintx4*)(Vh + (size_t)(flat >> 6) * S_LEN + kk0 + (flat & 63));
    }
}
__device__ __forceinline__ void st2(unsigned short* dst, int tid, const uintx4 r[2]) {
#pragma unroll
    for (int i = 0; i < 2; ++i) {
        int flat = tid * 8 + i * 2048;
        *(uintx4*)(dst + (flat >> 6) * KSTR + (flat & 63)) = r[i];
    }
}

__global__ __launch_bounds__(256, 2)
void attn_joint(const unsigned short* __restrict__ Qb, const unsigned short* __restrict__ Kb,
                const unsigned short* __restrict__ Vtg, const void* __restrict__ scp,
                float* __restrict__ Out, float* __restrict__ W)
{
    __shared__ unsigned short Kl[2][BK * KSTR];   // double-buffered K
    __shared__ unsigned short Vl[2][D_DIM * KSTR];// double-buffered V^T

    const int tid  = threadIdx.x;
    const int wave = tid >> 6;
    const int lane = tid & 63;
    const int quad = lane >> 4;
    const int lm   = lane & 15;
    const int idx  = blockIdx.x;
    const int bh   = idx & (BH - 1);
    const int j    = idx >> 5;                 // 0..15
    const int qtA  = j;                        // light q-tile
    const int qtB  = (NQT - 1) - j;            // heavy q-tile (qtA < qtB always)
    const int q0A  = qtA * BQ, q0B = qtB * BQ;

    const unsigned int sw = *(const unsigned int*)scp;
    const bool isf32 = ((sw & 0xFFFFu) == 0u);
    const float sc = isf32 ? __builtin_bit_cast(float, sw)
                           : __builtin_bit_cast(float, (sw & 0xFFFFu) << 16);
    const float sc2 = sc * 1.44269504088896f;   // base-2 softmax

    float* Ob = Out + (size_t)bh * S_LEN * D_DIM;
    float* Wb = W   + (size_t)bh * S_LEN * S_LEN;
    const unsigned short* Qh = Qb  + (size_t)bh * S_LEN * D_DIM;
    const unsigned short* Kh = Kb  + (size_t)bh * S_LEN * D_DIM;
    const unsigned short* Vh = Vtg + (size_t)bh * D_DIM * S_LEN;

    // zero-fill masked weights strips for both q-tiles (uniform total per block)
    {
        floatx4 z4 = {0.f, 0.f, 0.f, 0.f};
        const int zcA = S_LEN - (q0A + BQ);
        for (int r = 0; r < BQ; ++r) {
            float* wr = Wb + (size_t)(q0A + r) * S_LEN + (q0A + BQ);
            for (int c = tid * 4; c < zcA; c += 256 * 4)
                __builtin_nontemporal_store(z4, (floatx4*)(wr + c));
        }
        const int zcB = S_LEN - (q0B + BQ);
        for (int r = 0; r < BQ; ++r) {
            float* wr = Wb + (size_t)(q0B + r) * S_LEN + (q0B + BQ);
            for (int c = tid * 4; c < zcB; c += 256 * 4)
                __builtin_nontemporal_store(z4, (floatx4*)(wr + c));
        }
    }

    // Q fragments for both q-tiles, resident all kernel
    const int qrowA = q0A + wave * 16 + lm;
    const int qrowB = q0B + wave * 16 + lm;
    const short8 qfA0 = *(const short8*)(Qh + (size_t)qrowA * D_DIM + quad * 8);
    const short8 qfA1 = *(const short8*)(Qh + (size_t)qrowA * D_DIM + 32 + quad * 8);
    const short8 qfB0 = *(const short8*)(Qh + (size_t)qrowB * D_DIM + quad * 8);
    const short8 qfB1 = *(const short8*)(Qh + (size_t)qrowB * D_DIM + 32 + quad * 8);

    // =========== PASS 1: row sums for both q-tiles (no max; exp2 safe) ===========
    // Swapped MFMA: C[k][q] -> lane holds k-values of q-row q=lm.
    {
        uintx4 kr[2];
        ldK(Kh, 0, tid, kr); st2(Kl[0], tid, kr);
    }
    __syncthreads();

    float lsA0 = 0.f, lsA1 = 0.f, lsA2 = 0.f, lsA3 = 0.f;
    float lsB0 = 0.f, lsB1 = 0.f, lsB2 = 0.f, lsB3 = 0.f;
    for (int kt = 0; kt <= qtB; ++kt) {
        const bool pre  = (kt < qtB);
        const bool actA = (kt <= qtA);
        uintx4 kreg[2];
        if (pre) ldK(Kh, (kt + 1) * BK, tid, kreg);       // T14: issue early
        const unsigned short* Kc = Kl[kt & 1];
        const int kk0 = kt * BK;
        const bool diagA = (kt == qtA), diagB = (kt == qtB);
#pragma unroll
        for (int kkt = 0; kkt < 4; ++kkt) {
            short8 b0 = *(const short8*)(Kc + (kkt * 16 + lm) * KSTR + quad * 8);
            short8 b1 = *(const short8*)(Kc + (kkt * 16 + lm) * KSTR + 32 + quad * 8);
            const int kg = kk0 + kkt * 16 + quad * 4;      // k-global of acc[0]
            {   // heavy q-tile B (always active)
                floatx4 acc = {0.f, 0.f, 0.f, 0.f};
                acc = __builtin_amdgcn_mfma_f32_16x16x32_bf16(b0, qfB0, acc, 0, 0, 0);
                acc = __builtin_amdgcn_mfma_f32_16x16x32_bf16(b1, qfB1, acc, 0, 0, 0);
                float s0 = acc[0] * sc2, s1 = acc[1] * sc2;
                float s2 = acc[2] * sc2, s3 = acc[3] * sc2;
                if (diagB) {
                    if (kg + 0 > qrowB) s0 = -1e30f;
                    if (kg + 1 > qrowB) s1 = -1e30f;
                    if (kg + 2 > qrowB) s2 = -1e30f;
                    if (kg + 3 > qrowB) s3 = -1e30f;
                }
                lsB0 += exp2f(s0); lsB1 += exp2f(s1);
                lsB2 += exp2f(s2); lsB3 += exp2f(s3);
            }
            if (actA) {  // light q-tile A shares the same staged K fragments
                floatx4 acc = {0.f, 0.f, 0.f, 0.f};
                acc = __builtin_amdgcn_mfma_f32_16x16x32_bf16(b0, qfA0, acc, 0, 0, 0);
                acc = __builtin_amdgcn_mfma_f32_16x16x32_bf16(b1, qfA1, acc, 0, 0, 0);
                float s0 = acc[0] * sc2, s1 = acc[1] * sc2;
                float s2 = acc[2] * sc2, s3 = acc[3] * sc2;
                if (diagA) {
                    if (kg + 0 > qrowA) s0 = -1e30f;
                    if (kg + 1 > qrowA) s1 = -1e30f;
                    if (kg + 2 > qrowA) s2 = -1e30f;
                    if (kg + 3 > qrowA) s3 = -1e30f;
                }
                lsA0 += exp2f(s0); lsA1 += exp2f(s1);
                lsA2 += exp2f(s2); lsA3 += exp2f(s3);
            }
        }
        if (pre) st2(Kl[(kt + 1) & 1], tid, kreg);        // T14: write late
        __syncthreads();
    }
    float lsA = (lsA0 + lsA1) + (lsA2 + lsA3);
    float lsB = (lsB0 + lsB1) + (lsB2 + lsB3);
    lsA += __shfl_xor(lsA, 16, 64);  lsA += __shfl_xor(lsA, 32, 64);
    lsB += __shfl_xor(lsB, 16, 64);  lsB += __shfl_xor(lsB, 32, 64);
    const float linvA = 1.0f / lsA;   // row sum for q-row = lm (uniform over quads)
    const float linvB = 1.0f / lsB;

    // ===== PASS 2: swapped-score recompute, W from regs, PV via permlane transpose =====
    {
        uintx4 kr[2], vr[2];
        ldK(Kh, 0, tid, kr); ldV(Vh, 0, tid, vr);
        st2(Kl[0], tid, kr); st2(Vl[0], tid, vr);
    }
    __syncthreads();

    floatx4 oaccA[4], oaccB[4];
#pragma unroll
    for (int dt = 0; dt < 4; ++dt) {
        oaccA[dt] = (floatx4){0.f, 0.f, 0.f, 0.f};
        oaccB[dt] = (floatx4){0.f, 0.f, 0.f, 0.f};
    }

    for (int kt = 0; kt <= qtB; ++kt) {
        const bool pre  = (kt < qtB);
        const bool actA = (kt <= qtA);
        uintx4 kreg[2], vreg[2];
        if (pre) { ldK(Kh, (kt + 1) * BK, tid, kreg); ldV(Vh, (kt + 1) * BK, tid, vreg); }
        const unsigned short* Kc = Kl[kt & 1];
        const unsigned short* Vc = Vl[kt & 1];
        const int kk0 = kt * BK;
        const bool diagA = (kt == qtA), diagB = (kt == qtB);

        unsigned int ddA[4][2], ddB[4][2];                // bf16 P pairs, pre-transpose
#pragma unroll
        for (int kkt = 0; kkt < 4; ++kkt) {               // swapped scores: lane q = lm
            short8 b0 = *(const short8*)(Kc + (kkt * 16 + lm) * KSTR + quad * 8);
            short8 b1 = *(const short8*)(Kc + (kkt * 16 + lm) * KSTR + 32 + quad * 8);
            const int kg = kk0 + kkt * 16 + quad * 4;     // k of acc[0]
            {   // q-tile B
                floatx4 acc = {0.f, 0.f, 0.f, 0.f};
                acc = __builtin_amdgcn_mfma_f32_16x16x32_bf16(b0, qfB0, acc, 0, 0, 0);
                acc = __builtin_amdgcn_mfma_f32_16x16x32_bf16(b1, qfB1, acc, 0, 0, 0);
                float s0 = acc[0] * sc2, s1 = acc[1] * sc2;
                float s2 = acc[2] * sc2, s3 = acc[3] * sc2;
                if (diagB) {
                    if (kg + 0 > qrowB) s0 = -1e30f;
                    if (kg + 1 > qrowB) s1 = -1e30f;
                    if (kg + 2 > qrowB) s2 = -1e30f;
                    if (kg + 3 > qrowB) s3 = -1e30f;
                }
                float p0 = exp2f(s0) * linvB, p1 = exp2f(s1) * linvB;
                float p2 = exp2f(s2) * linvB, p3 = exp2f(s3) * linvB;
                floatx4 w4; w4[0] = p0; w4[1] = p1; w4[2] = p2; w4[3] = p3;
                __builtin_nontemporal_store(w4, (floatx4*)(Wb + (size_t)qrowB * S_LEN + kg));
                asm("v_cvt_pk_bf16_f32 %0, %1, %2" : "=v"(ddB[kkt][0]) : "v"(p0), "v"(p1));
                asm("v_cvt_pk_bf16_f32 %0, %1, %2" : "=v"(ddB[kkt][1]) : "v"(p2), "v"(p3));
            }
            if (actA) {  // q-tile A shares the same K fragments
                floatx4 acc = {0.f, 0.f, 0.f, 0.f};
                acc = __builtin_amdgcn_mfma_f32_16x16x32_bf16(b0, qfA0, acc, 0, 0, 0);
                acc = __builtin_amdgcn_mfma_f32_16x16x32_bf16(b1, qfA1, acc, 0, 0, 0);
                float s0 = acc[0] * sc2, s1 = acc[1] * sc2;
                float s2 = acc[2] * sc2, s3 = acc[3] * sc2;
                if (diagA) {
                    if (kg + 0 > qrowA) s0 = -1e30f;
                    if (kg + 1 > qrowA) s1 = -1e30f;
                    if (kg + 2 > qrowA) s2 = -1e30f;
                    if (kg + 3 > qrowA) s3 = -1e30f;
                }
                float p0 = exp2f(s0) * linvA, p1 = exp2f(s1) * linvA;
                float p2 = exp2f(s2) * linvA, p3 = exp2f(s3) * linvA;
                floatx4 w4; w4[0] = p0; w4[1] = p1; w4[2] = p2; w4[3] = p3;
                __builtin_nontemporal_store(w4, (floatx4*)(Wb + (size_t)qrowA * S_LEN + kg));
                asm("v_cvt_pk_bf16_f32 %0, %1, %2" : "=v"(ddA[kkt][0]) : "v"(p0), "v"(p1));
                asm("v_cvt_pk_bf16_f32 %0, %1, %2" : "=v"(ddA[kkt][1]) : "v"(p2), "v"(p3));
            }
        }
        // 4x4 quad transpose in-register (verified R3): rotation (b5,b4,t)->(t,b5,b4)
#pragma unroll
        for (int c = 0; c < 2; ++c) {
            asm("v_permlane32_swap_b32 %0, %1" : "+v"(ddB[2*c][0]), "+v"(ddB[2*c+1][0]));
            asm("v_permlane32_swap_b32 %0, %1" : "+v"(ddB[2*c][1]), "+v"(ddB[2*c+1][1]));
            asm("v_permlane16_swap_b32 %0, %1" : "+v"(ddB[2*c][0]), "+v"(ddB[2*c+1][0]));
            asm("v_permlane16_swap_b32 %0, %1" : "+v"(ddB[2*c][1]), "+v"(ddB[2*c+1][1]));
        }
        if (actA) {
#pragma unroll
            for (int c = 0; c < 2; ++c) {
                asm("v_permlane32_swap_b32 %0, %1" : "+v"(ddA[2*c][0]), "+v"(ddA[2*c+1][0]));
                asm("v_permlane32_swap_b32 %0, %1" : "+v"(ddA[2*c][1]), "+v"(ddA[2*c+1][1]));
                asm("v_permlane16_swap_b32 %0, %1" : "+v"(ddA[2*c][0]), "+v"(ddA[2*c+1][0]));
                asm("v_permlane16_swap_b32 %0, %1" : "+v"(ddA[2*c][1]), "+v"(ddA[2*c+1][1]));
            }
        }
#pragma unroll
        for (int c = 0; c < 2; ++c) {                     // O += P * V (shared V frags)
            uintx4 pb_;
            pb_[0] = ddB[2*c][0]; pb_[1] = ddB[2*c][1];
            pb_[2] = ddB[2*c+1][0]; pb_[3] = ddB[2*c+1][1];
            short8 pfB = __builtin_bit_cast(short8, pb_);
            uintx4 pa_;
            pa_[0] = ddA[2*c][0]; pa_[1] = ddA[2*c][1];
            pa_[2] = ddA[2*c+1][0]; pa_[3] = ddA[2*c+1][1];
            short8 pfA = __builtin_bit_cast(short8, pa_);
#pragma unroll
            for (int dt = 0; dt < 4; ++dt) {
                short8 vf = *(const short8*)(Vc + (dt * 16 + lm) * KSTR + c * 32 + quad * 8);
                oaccB[dt] = __builtin_amdgcn_mfma_f32_16x16x32_bf16(pfB, vf, oaccB[dt], 0, 0, 0);
                if (actA)
                    oaccA[dt] = __builtin_amdgcn_mfma_f32_16x16x32_bf16(pfA, vf, oaccA[dt], 0, 0, 0);
            }
        }

        if (pre) {
            st2(Kl[(kt + 1) & 1], tid, kreg);   // other buffers: nobody reads them now
            st2(Vl[(kt + 1) & 1], tid, vreg);
            __syncthreads();                    // single barrier per tile
        }
    }

    // ---- epilogue: O stored fp32 directly from accumulators (C-layout) ----
#pragma unroll
    for (int dt = 0; dt < 4; ++dt)
#pragma unroll
        for (int r = 0; r < 4; ++r) {
            Ob[(size_t)(q0B + wave * 16 + quad * 4 + r) * D_DIM + dt * 16 + lm] = oaccB[dt][r];
            Ob[(size_t)(q0A + wave * 16 + quad * 4 + r) * D_DIM + dt * 16 + lm] = oaccA[dt][r];
        }
}

// ============================================================================
// FALLBACK (verified R0 kernel) -- used only if ws_size is too small
// ============================================================================
template<typename TIN>
__device__ __forceinline__ void stageK(const TIN* Kb, int kk0, __hip_bfloat16* Kl, int tid) {
    if constexpr (sizeof(TIN) == 4) {
#pragma unroll
        for (int i = 0; i < 4; ++i) {
            int flat = tid * 4 + i * 1024;
            int row = flat >> 6, col = flat & 63;
            floatx4 v = *(const floatx4*)((const float*)Kb + (size_t)(kk0 + row) * D_DIM + col);
            short4v s;
            s[0]=(short)f2bf(v[0]); s[1]=(short)f2bf(v[1]);
            s[2]=(short)f2bf(v[2]); s[3]=(short)f2bf(v[3]);
            *(short4v*)(&Kl[row * KSTR + col]) = s;
        }
    } else {
#pragma unroll
        for (int i = 0; i < 2; ++i) {
            int flat = tid * 8 + i * 2048;
            int row = flat >> 6, col = flat & 63;
            *(uintx4*)(&Kl[row * KSTR + col]) =
                *(const uintx4*)((const __hip_bfloat16*)Kb + (size_t)(kk0 + row) * D_DIM + col);
        }
    }
}

template<typename TIN>
__device__ __forceinline__ void attn_body(
    const TIN* __restrict__ Qb, const TIN* __restrict__ Kb, const TIN* __restrict__ Vb,
    float sc2, float* __restrict__ Ob, float* __restrict__ Wb,
    int q0, int qt, __hip_bfloat16* Kl, __hip_bfloat16* Vt, __hip_bfloat16* Plw)
{
    const int tid  = threadIdx.x;
    const int wave = tid >> 6;
    const int lane = tid & 63;
    const int quad = lane >> 4;
    const int lm   = lane & 15;

    const int qrow = q0 + wave * 16 + lm;
    short8 qfrag0 = load8(Qb + (size_t)qrow * D_DIM + quad * 8);
    short8 qfrag1 = load8(Qb + (size_t)qrow * D_DIM + 32 + quad * 8);

    float mrow[4], lrow[4];
#pragma unroll
    for (int r = 0; r < 4; ++r) { mrow[r] = -1e30f; lrow[r] = 0.f; }

    for (int kt = 0; kt <= qt; ++kt) {
        const int kk0 = kt * BK;
        __syncthreads();
        stageK(Kb, kk0, Kl, tid);
        __syncthreads();

        const bool diag = (kt == qt);
        float s[4][4];
#pragma unroll
        for (int kkt = 0; kkt < 4; ++kkt) {
            floatx4 acc = {0.f, 0.f, 0.f, 0.f};
            short8 b0 = *(const short8*)(&Kl[(kkt * 16 + lm) * KSTR + quad * 8]);
            short8 b1 = *(const short8*)(&Kl[(kkt * 16 + lm) * KSTR + 32 + quad * 8]);
            acc = __builtin_amdgcn_mfma_f32_16x16x32_bf16(qfrag0, b0, acc, 0, 0, 0);
            acc = __builtin_amdgcn_mfma_f32_16x16x32_bf16(qfrag1, b1, acc, 0, 0, 0);
#pragma unroll
            for (int r = 0; r < 4; ++r) s[kkt][r] = acc[r] * sc2;
            if (diag) {
                int colg = kk0 + kkt * 16 + lm;
#pragma unroll
                for (int r = 0; r < 4; ++r) {
                    int rowg = q0 + wave * 16 + quad * 4 + r;
                    if (colg > rowg) s[kkt][r] = -1e30f;
                }
            }
        }
#pragma unroll
        for (int r = 0; r < 4; ++r) {
            float mx = fmaxf(fmaxf(s[0][r], s[1][r]), fmaxf(s[2][r], s[3][r]));
#pragma unroll
            for (int off = 1; off < 16; off <<= 1)
                mx = fmaxf(mx, __shfl_xor(mx, off, 64));
            float mnew = fmaxf(mrow[r], mx);
            float p = exp2f(s[0][r] - mnew) + exp2f(s[1][r] - mnew) +
                      exp2f(s[2][r] - mnew) + exp2f(s[3][r] - mnew);
#pragma unroll
            for (int off = 1; off < 16; off <<= 1)
                p += __shfl_xor(p, off, 64);
            lrow[r] = lrow[r] * exp2f(mrow[r] - mnew) + p;
            mrow[r] = mnew;
        }
    }

    float inv_l[4];
#pragma unroll
    for (int r = 0; r < 4; ++r) inv_l[r] = 1.0f / lrow[r];

    floatx4 oacc[4];
#pragma unroll
    for (int dt = 0; dt < 4; ++dt) oacc[dt] = (floatx4){0.f, 0.f, 0.f, 0.f};

    for (int kt = 0; kt <= qt; ++kt) {
        const int kk0 = kt * BK;
        __syncthreads();
        stageK(Kb, kk0, Kl, tid);
        {
            int r = tid & 31, c = (tid >> 5) << 3;
            const TIN* v0 = Vb + (size_t)(kk0 + 2 * r) * D_DIM + c;
            unsigned short a[8], b[8];
            loadrow8(v0, a);
            loadrow8(v0 + D_DIM, b);
#pragma unroll
            for (int j = 0; j < 8; ++j) {
                unsigned int d = (unsigned int)a[j] | ((unsigned int)b[j] << 16);
                *(unsigned int*)(&Vt[(c + j) * KSTR + 2 * r]) = d;
            }
        }
        __syncthreads();

        const bool diag = (kt == qt);
        float s[4][4];
#pragma unroll
        for (int kkt = 0; kkt < 4; ++kkt) {
            floatx4 acc = {0.f, 0.f, 0.f, 0.f};
            short8 b0 = *(const short8*)(&Kl[(kkt * 16 + lm) * KSTR + quad * 8]);
            short8 b1 = *(const short8*)(&Kl[(kkt * 16 + lm) * KSTR + 32 + quad * 8]);
            acc = __builtin_amdgcn_mfma_f32_16x16x32_bf16(qfrag0, b0, acc, 0, 0, 0);
            acc = __builtin_amdgcn_mfma_f32_16x16x32_bf16(qfrag1, b1, acc, 0, 0, 0);
#pragma unroll
            for (int r = 0; r < 4; ++r) s[kkt][r] = acc[r] * sc2;
            if (diag) {
                int colg = kk0 + kkt * 16 + lm;
#pragma unroll
                for (int r = 0; r < 4; ++r) {
                    int rowg = q0 + wave * 16 + quad * 4 + r;
                    if (colg > rowg) s[kkt][r] = -1e30f;
                }
            }
        }
#pragma unroll
        for (int kkt = 0; kkt < 4; ++kkt) {
#pragma unroll
            for (int r = 0; r < 4; ++r) {
                float p = exp2f(s[kkt][r] - mrow[r]) * inv_l[r];
                Plw[(quad * 4 + r) * KSTR + kkt * 16 + lm] =
                    __builtin_bit_cast(__hip_bfloat16, f2bf(p));
            }
        }
        __asm__ volatile("s_waitcnt lgkmcnt(0)" ::: "memory");

        {
            int rr = lane >> 3, cc = (lane & 7) << 3;
            short8 w0 = *(const short8*)(&Plw[rr * KSTR + cc]);
            short8 w1 = *(const short8*)(&Plw[(8 + rr) * KSTR + cc]);
            float* wp0 = Wb + (size_t)(q0 + wave * 16 + rr) * S_LEN + kk0 + cc;
            float* wp1 = Wb + (size_t)(q0 + wave * 16 + 8 + rr) * S_LEN + kk0 + cc;
            floatx4 fa, fb;
#pragma unroll
            for (int j = 0; j < 4; ++j) { fa[j] = bf2f(w0[j]); fb[j] = bf2f(w0[4 + j]); }
            *(floatx4*)wp0 = fa; *(floatx4*)(wp0 + 4) = fb;
#pragma unroll
            for (int j = 0; j < 4; ++j) { fa[j] = bf2f(w1[j]); fb[j] = bf2f(w1[4 + j]); }
            *(floatx4*)wp1 = fa; *(floatx4*)(wp1 + 4) = fb;
        }
#pragma unroll
        for (int c = 0; c < 2; ++c) {
            short8 pf = *(const short8*)(&Plw[lm * KSTR + c * 32 + quad * 8]);
#pragma unroll
            for (int dt = 0; dt < 4; ++dt) {
                short8 vf = *(const short8*)(&Vt[(dt * 16 + lm) * KSTR + c * 32 + quad * 8]);
                oacc[dt] = __builtin_amdgcn_mfma_f32_16x16x32_bf16(pf, vf, oacc[dt], 0, 0, 0);
            }
        }
    }

#pragma unroll
    for (int dt = 0; dt < 4; ++dt)
#pragma unroll
        for (int r = 0; r < 4; ++r)
            Ob[(size_t)(q0 + wave * 16 + quad * 4 + r) * D_DIM + dt * 16 + lm] = oacc[dt][r];
}

__global__ __launch_bounds__(256, 4)
void attn_kernel(const void* __restrict__ Q, const void* __restrict__ K,
                 const void* __restrict__ V, const void* __restrict__ scp,
                 float* __restrict__ Out, float* __restrict__ W)
{
    __shared__ __hip_bfloat16 Kl[BK * KSTR];
    __shared__ __hip_bfloat16 Vt[D_DIM * KSTR];
    __shared__ __hip_bfloat16 Pl[4][16 * KSTR];

    const int tid  = threadIdx.x;
    const int wave = tid >> 6;
    const int idx  = blockIdx.x;
    const int bh   = idx & (BH - 1);
    const int qt   = (NQT - 1) - (idx >> 5);
    const int q0   = qt * BQ;

    const size_t bqd = (size_t)bh * S_LEN * D_DIM;
    float* Ob = Out + bqd;
    float* Wb = W + (size_t)bh * S_LEN * S_LEN;

    const unsigned int sw = *(const unsigned int*)scp;
    const bool isf32 = ((sw & 0xFFFFu) == 0u);
    const float sc = isf32 ? __builtin_bit_cast(float, sw)
                           : __builtin_bit_cast(float, (sw & 0xFFFFu) << 16);
    const float sc2 = sc * 1.44269504088896f;

    {
        const int zc = S_LEN - (q0 + BQ);
        floatx4 z4 = {0.f, 0.f, 0.f, 0.f};
        for (int r = 0; r < BQ; ++r) {
            float* wr = Wb + (size_t)(q0 + r) * S_LEN + (q0 + BQ);
            for (int c = tid * 4; c < zc; c += 256 * 4)
                *(floatx4*)(wr + c) = z4;
        }
    }

    if (isf32)
        attn_body<float>((const float*)Q + bqd, (const float*)K + bqd,
                         (const float*)V + bqd, sc2, Ob, Wb, q0, qt, Kl, Vt, Pl[wave]);
    else
        attn_body<__hip_bfloat16>((const __hip_bfloat16*)Q + bqd, (const __hip_bfloat16*)K + bqd,
                                  (const __hip_bfloat16*)V + bqd, sc2, Ob, Wb, q0, qt, Kl, Vt, Pl[wave]);
}

extern "C" void kernel_launch(void* const* d_in, const int* in_sizes, int n_in,
                              void* d_out, int out_size, void* d_ws, size_t ws_size,
                              hipStream_t stream) {
    float* Outp = (float*)d_out;                           // [B,H,S,D] fp32
    float* Wp   = Outp + NEL;                              // [B,H,S,S] fp32

    const size_t need = NEL * 3 * sizeof(unsigned short);  // 25.2 MB bf16 Q,K,V^T
    if (d_ws != nullptr && ws_size >= need) {
        unsigned short* Qb  = (unsigned short*)d_ws;
        unsigned short* Kb  = Qb + NEL;
        unsigned short* Vtg = Kb + NEL;
        prep_kernel<<<dim3(NQT * BH), dim3(256), 0, stream>>>(
            d_in[0], d_in[1], d_in[2], d_in[3], Qb, Kb, Vtg);
        attn_joint<<<dim3(NPAIR * BH), dim3(256), 0, stream>>>(
            Qb, Kb, Vtg, d_in[3], Outp, Wp);
    } else {
        attn_kernel<<<dim3(NQT * BH), dim3(256), 0, stream>>>(
            d_in[0], d_in[1], d_in[2], d_in[3], Outp, Wp);
    }
}